// Round 1
// baseline (127.908 us; speedup 1.0000x reference)
//
#include <hip/hip_runtime.h>
#include <math.h>

// NoiseGenerator: out[n][b] = (y1[n][b] - y2[n][b]) * env[n][b]   (gain folded into y)
//   y1[n] = f_lp*y1[n-1] + (1-f_lp)*gain*noise[n]        (gain-scaled lowpass)
//   y2[n] = f_hp*y2[n-1] + (1-f_hp)*y1[n]                (lowpass of y1; hp = y1-y2)
//   env[n] = (1 - exp(-t/(attack+eps))) * exp(-t/(decay+eps)),  t = n/48000
//
// 3-phase exact chunked linear-recurrence scan (M is constant per column):
//   A: per (chunk, col): run L samples from zero state -> chunk aggregate V_c
//   B: per col: M^L via homogeneous recurrence (cancellation-safe), serial scan
//      over 240 chunks -> entry state per chunk (overwrites ws in place)
//   C: per (chunk, col): run L samples from entry state, apply envelope
//      (incremental exp, re-anchored per chunk), float2 streaming stores.

#define NSAMP   24000
#define NBATCH  1024
#define LCHUNK  100
#define NCHUNK  240            // NSAMP / LCHUNK
#define CPT     2              // columns per thread -> float2 stores
#define TPB     256
#define COLS_PER_BLOCK (TPB*CPT)        // 512
#define NCOLGRP (NBATCH/COLS_PER_BLOCK) // 2
#define EPSF    1e-4f
#define DT      (1.0f/48000.0f)

// ---------------- Phase A: chunk aggregates (zero entry state) ----------------
__global__ __launch_bounds__(TPB) void kA(const float* __restrict__ par,
                                          const float* __restrict__ noise,
                                          float* __restrict__ wy1,
                                          float* __restrict__ wy2) {
    const int c    = blockIdx.x;
    const int col0 = blockIdx.y * COLS_PER_BLOCK + threadIdx.x * CPT;

    __shared__ float xs[LCHUNK];
    if (threadIdx.x < LCHUNK) xs[threadIdx.x] = noise[c * LCHUNK + threadIdx.x];
    __syncthreads();

    float a1[CPT], c1[CPT], a2[CPT], c2[CPT], y1[CPT], y2[CPT];
#pragma unroll
    for (int k = 0; k < CPT; ++k) {
        const int b = col0 + k;
        a1[k] = par[2 * NBATCH + b];                 // f_lp
        a2[k] = par[3 * NBATCH + b];                 // f_hp
        const float g = par[4 * NBATCH + b];         // gain
        c1[k] = (1.0f - a1[k]) * g;                  // gain folded in (matches kC)
        c2[k] = 1.0f - a2[k];
        y1[k] = 0.0f; y2[k] = 0.0f;
    }

#pragma unroll 4
    for (int i = 0; i < LCHUNK; ++i) {
        const float x = xs[i];
#pragma unroll
        for (int k = 0; k < CPT; ++k) {
            y1[k] = a1[k] * y1[k] + c1[k] * x;
            y2[k] = a2[k] * y2[k] + c2[k] * y1[k];
        }
    }
    *reinterpret_cast<float2*>(&wy1[c * NBATCH + col0]) = make_float2(y1[0], y1[1]);
    *reinterpret_cast<float2*>(&wy2[c * NBATCH + col0]) = make_float2(y2[0], y2[1]);
}

// ---------------- Phase B: per-column serial scan over chunks ----------------
__global__ __launch_bounds__(TPB) void kB(const float* __restrict__ par,
                                          float* __restrict__ wy1,
                                          float* __restrict__ wy2) {
    const int b = blockIdx.x * TPB + threadIdx.x;    // 0..1023
    const float a1 = par[2 * NBATCH + b];
    const float a2 = par[3 * NBATCH + b];
    const float c2 = 1.0f - a2;

    // M^LCHUNK via homogeneous recurrence: start (1,0) -> (a1^L, mL); a2^L separately.
    // (closed form (a1^L-a2^L)/(a1-a2) cancels catastrophically when f_lp ~ f_hp)
    float u1 = 1.0f, u2 = 0.0f, u3 = 1.0f;
    for (int i = 0; i < LCHUNK; ++i) {
        u1 = a1 * u1;
        u2 = a2 * u2 + c2 * u1;
        u3 = a2 * u3;
    }
    const float p1 = u1, mL = u2, p2 = u3;

    float s1 = 0.0f, s2 = 0.0f;                      // entry state of chunk 0
#pragma unroll 8
    for (int c = 0; c < NCHUNK; ++c) {
        const float v1 = wy1[c * NBATCH + b];
        const float v2 = wy2[c * NBATCH + b];
        wy1[c * NBATCH + b] = s1;                    // overwrite aggregate with entry
        wy2[c * NBATCH + b] = s2;
        const float ns1 = p1 * s1 + v1;              // state after chunk c
        const float ns2 = mL * s1 + (p2 * s2 + v2);
        s1 = ns1; s2 = ns2;
    }
}

// ---------------- Phase C: output pass with envelope ----------------
__global__ __launch_bounds__(TPB) void kC(const float* __restrict__ par,
                                          const float* __restrict__ noise,
                                          const float* __restrict__ wy1,
                                          const float* __restrict__ wy2,
                                          float* __restrict__ out) {
    const int c    = blockIdx.x;
    const int col0 = blockIdx.y * COLS_PER_BLOCK + threadIdx.x * CPT;

    __shared__ float xs[LCHUNK];
    if (threadIdx.x < LCHUNK) xs[threadIdx.x] = noise[c * LCHUNK + threadIdx.x];
    __syncthreads();

    float a1[CPT], c1[CPT], a2[CPT], c2[CPT], y1[CPT], y2[CPT];
    float ea[CPT], ra[CPT], ed[CPT], rd[CPT];
    const float t0 = (float)(c * LCHUNK) * DT;
#pragma unroll
    for (int k = 0; k < CPT; ++k) {
        const int b = col0 + k;
        const float att = par[b] + EPSF;
        const float dec = par[NBATCH + b] + EPSF;
        a1[k] = par[2 * NBATCH + b];
        a2[k] = par[3 * NBATCH + b];
        const float g = par[4 * NBATCH + b];
        c1[k] = (1.0f - a1[k]) * g;
        c2[k] = 1.0f - a2[k];
        const float ia  = 1.0f / att;
        const float idc = 1.0f / dec;
        ea[k] = expf(-t0 * ia);   ra[k] = expf(-DT * ia);   // re-anchored per chunk:
        ed[k] = expf(-t0 * idc);  rd[k] = expf(-DT * idc);  // drift ~ L*eps ~ 6e-6 rel
        y1[k] = wy1[c * NBATCH + b];                        // entry state
        y2[k] = wy2[c * NBATCH + b];
    }

    float2* op = reinterpret_cast<float2*>(out + (size_t)c * LCHUNK * NBATCH + col0);
#pragma unroll 4
    for (int i = 0; i < LCHUNK; ++i) {
        const float x = xs[i];
        float2 o;
#pragma unroll
        for (int k = 0; k < CPT; ++k) {
            y1[k] = a1[k] * y1[k] + c1[k] * x;
            y2[k] = a2[k] * y2[k] + c2[k] * y1[k];
            const float env = (1.0f - ea[k]) * ed[k];
            (&o.x)[k] = (y1[k] - y2[k]) * env;
            ea[k] *= ra[k];
            ed[k] *= rd[k];
        }
        *op = o;                   // out[(c*L+i)*NBATCH + col0], 8B/lane coalesced
        op += NBATCH / 2;
    }
}

extern "C" void kernel_launch(void* const* d_in, const int* in_sizes, int n_in,
                              void* d_out, int out_size, void* d_ws, size_t ws_size,
                              hipStream_t stream) {
    const float* par   = (const float*)d_in[0];   // [5, 1024]
    const float* noise = (const float*)d_in[1];   // [24000]
    float* out = (float*)d_out;                   // [24000, 1024]
    float* wy1 = (float*)d_ws;                    // [NCHUNK][NBATCH]
    float* wy2 = wy1 + (size_t)NCHUNK * NBATCH;   // [NCHUNK][NBATCH]  (~1.97 MB total)

    const dim3 grid(NCHUNK, NCOLGRP), block(TPB);
    kA<<<grid, block, 0, stream>>>(par, noise, wy1, wy2);
    kB<<<dim3(NBATCH / TPB), block, 0, stream>>>(par, wy1, wy2);
    kC<<<grid, block, 0, stream>>>(par, noise, wy1, wy2, out);
}